// Round 12
// baseline (199.477 us; speedup 1.0000x reference)
//
#include <hip/hip_runtime.h>
#include <hip/hip_bf16.h>
#include <math.h>

#define BDIM  4
#define NFEAT 2048
#define DDIM  256
#define KCENT 16384
#define TK    5
#define NCB   4
#define CBSZ  (KCENT / NCB)   // 4096
#define KB    128             // centroids per tile
#define NT    (CBSZ / KB)     // 32
#define FB    128             // features per block
#define RESC  12              // exactly-rescored candidates per feature
#define NROW  (BDIM * KCENT)  // 65536
#define INFF  (__builtin_inff())

typedef __attribute__((ext_vector_type(4))) float  f32x4;
typedef __attribute__((ext_vector_type(8))) short  short8v;

static __device__ __forceinline__ short f2bf(float x) {
  __hip_bfloat16 h = __float2bfloat16(x);
  return __builtin_bit_cast(short, h);
}

static __device__ __forceinline__ float wsum(float v) {
  v += __shfl_xor(v, 1);  v += __shfl_xor(v, 2);  v += __shfl_xor(v, 4);
  v += __shfl_xor(v, 8);  v += __shfl_xor(v, 16); v += __shfl_xor(v, 32);
  return v;
}
static __device__ __forceinline__ unsigned med3u(unsigned a, unsigned b, unsigned c) {
  unsigned d;
  asm("v_med3_u32 %0, %1, %2, %3" : "=v"(d) : "v"(a), "v"(b), "v"(c));
  return d;
}

// ---- fused prep: F->bf16 | C->bf16 + c2 | zero cnt (cnt OUTSIDE Xbf!) ------
__global__ __launch_bounds__(256) void k_cvtall(const float* __restrict__ F,
                                                const float* __restrict__ C,
                                                short* __restrict__ Xbf,
                                                short* __restrict__ Cbf,
                                                float* __restrict__ c2,
                                                unsigned* __restrict__ cnt) {
  if (blockIdx.x < 1024) {
    const int i = blockIdx.x * 256 + threadIdx.x;      // 262144 x 8 elems
    const float4* s = (const float4*)F + (size_t)i * 2;
    const float4 a = s[0], b = s[1];
    short8v o;
    o[0] = f2bf(a.x); o[1] = f2bf(a.y); o[2] = f2bf(a.z); o[3] = f2bf(a.w);
    o[4] = f2bf(b.x); o[5] = f2bf(b.y); o[6] = f2bf(b.z); o[7] = f2bf(b.w);
    ((short8v*)Xbf)[i] = o;
  } else if (blockIdx.x < 1024 + KCENT / 4) {
    const int w = threadIdx.x >> 6, l = threadIdx.x & 63;
    const int row = (blockIdx.x - 1024) * 4 + w;
    const float4 v = *(const float4*)(C + (size_t)row * DDIM + l * 4);
    short4 o;
    o.x = f2bf(v.x); o.y = f2bf(v.y); o.z = f2bf(v.z); o.w = f2bf(v.w);
    *(short4*)(Cbf + (size_t)row * DDIM + l * 4) = o;
    const float ss = wsum(v.x*v.x + v.y*v.y + v.z*v.z + v.w*v.w);
    if (l == 0) c2[row] = ss;
  } else {
    const int i = (blockIdx.x - (1024 + KCENT / 4)) * 256 + threadIdx.x;
    ((uint4*)cnt)[i] = make_uint4(0u, 0u, 0u, 0u);     // 64 blocks x 4 KB
  }
}

// ---- bf16 MFMA distance pass, med3 min-list, top-8/feature -----------------
// XCD-aware (fb,cb) decode: XCD = blockIdx%8 hosts only cb = (blockIdx&7)>>1,
// so each XCD's 4 MB L2 serves ONE 2 MB centroid slice (T1).
__global__ __launch_bounds__(1024, 4) void k_main(
    const short* __restrict__ Xbf, const short* __restrict__ Cbf,
    const float* __restrict__ c2g, uint2* __restrict__ cand)
{
  __shared__ short sC[2][KB * DDIM];   // 2 x 64 KB
  __shared__ float sC2a[CBSZ];         // 16 KB: whole split's biased c2

  const int tid = threadIdx.x;
  const int l = tid & 63, w = tid >> 6;        // w in [0,16)
  const int wm = w & 3, wn = w >> 2;           // 4 cent-groups x 4 feat-groups
  const int lrow = l & 15, lk = l >> 4;
  const int cb = (blockIdx.x & 7) >> 1;
  const int fb = (blockIdx.x >> 3) * 2 + (blockIdx.x & 1);
  const int fbase = fb * FB;
  const size_t coffB = (size_t)cb * CBSZ * (DDIM * 2);

  const int poff = (tid >> 9) * 8192 + (tid & 15) * 512 +
                   ((tid >> 6) & 7) * 64 + ((tid >> 4) & 3) * 16;

  auto stage = [&](const char* gsrcB, int buf) {   // 64 KB in 4 x (1024x16B)
#pragma unroll
    for (int r = 0; r < 4; ++r) {
      __builtin_amdgcn_global_load_lds(
          (const __attribute__((address_space(1))) void*)(gsrcB + r * 16384 + poff),
          (__attribute__((address_space(3))) void*)((char*)&sC[buf][0] + r * 16384 + tid * 16),
          16, 0, 0);
    }
  };

  stage((const char*)Xbf + (size_t)fbase * 512, 1);
  stage((const char*)Cbf + coffB, 0);
  {
    const f32x4* src = (const f32x4*)(c2g + cb * CBSZ);
    const f32x4 bias = {1024.f, 1024.f, 1024.f, 1024.f};
    ((f32x4*)sC2a)[tid] = src[tid] + bias;     // 1024 x 16B = 16 KB exactly
  }
  __syncthreads();

  // feature fragments -> registers (feature = wn*32 + nf*16 + lrow)
  short8v bfr[2][8];                            // 64 VGPR
#pragma unroll
  for (int nf = 0; nf < 2; ++nf) {
    const char* bp = (const char*)&sC[1][0] + (wn * 2 + nf) * 8192 + l * 16;
#pragma unroll
    for (int kk = 0; kk < 8; ++kk)
      bfr[nf][kk] = *(const short8v*)(bp + kk * 1024);
  }
  __syncthreads();   // buf1 free for staging

  const char* a0b0 = (const char*)&sC[0][0] + (wm * 2 + 0) * 8192 + l * 16;
  const char* a1b0 = (const char*)&sC[0][0] + (wm * 2 + 1) * 8192 + l * 16;
  const char* a0b1 = (const char*)&sC[1][0] + (wm * 2 + 0) * 8192 + l * 16;
  const char* a1b1 = (const char*)&sC[1][0] + (wm * 2 + 1) * 8192 + l * 16;

  unsigned kv[2][5];
#pragma unroll
  for (int nf = 0; nf < 2; ++nf)
#pragma unroll
    for (int j = 0; j < 5; ++j) kv[nf][j] = 0xFFFFFFFFu;

  for (int t = 0; t < NT; ++t) {
    const int buf = t & 1;
    if (t + 1 < NT) {
      stage((const char*)Cbf + coffB + (size_t)(t + 1) * (KB * 512), buf ^ 1);
      __builtin_amdgcn_sched_barrier(0);                 // stage pinned above
      asm volatile("s_waitcnt vmcnt(4)" ::: "memory");   // tile t's 4 retired
    } else {
      __builtin_amdgcn_sched_barrier(0);
      asm volatile("s_waitcnt vmcnt(0)" ::: "memory");
    }
    __builtin_amdgcn_s_barrier();                        // tile t landed (all)
    __builtin_amdgcn_sched_barrier(0);                   // no reads hoist above

    f32x4 acc[2][2];
    const f32x4 z = {0.f, 0.f, 0.f, 0.f};
#pragma unroll
    for (int mf = 0; mf < 2; ++mf)
#pragma unroll
      for (int nf = 0; nf < 2; ++nf) acc[mf][nf] = z;

    const char* ap0 = buf ? a0b1 : a0b0;
    const char* ap1 = buf ? a1b1 : a1b0;
#pragma unroll
    for (int kk = 0; kk < 8; ++kk) {
      const short8v a0 = *(const short8v*)(ap0 + kk * 1024);
      const short8v a1 = *(const short8v*)(ap1 + kk * 1024);
#pragma unroll
      for (int nf = 0; nf < 2; ++nf) {
        acc[0][nf] = __builtin_amdgcn_mfma_f32_16x16x32_bf16(a0, bfr[nf][kk], acc[0][nf], 0, 0, 0);
        acc[1][nf] = __builtin_amdgcn_mfma_f32_16x16x32_bf16(a1, bfr[nf][kk], acc[1][nf], 0, 0, 0);
      }
    }

    const f32x4 cb0 = *(const f32x4*)&sC2a[t * KB + wm * 32 + lk * 4];
    const f32x4 cb1 = *(const f32x4*)&sC2a[t * KB + wm * 32 + 16 + lk * 4];
#pragma unroll
    for (int mf = 0; mf < 2; ++mf)
#pragma unroll
      for (int r = 0; r < 4; ++r) {
        const float c2v = mf ? cb1[r] : cb0[r];
        const unsigned q = (unsigned)(t * 8 + mf * 4 + r);
#pragma unroll
        for (int nf = 0; nf < 2; ++nf) {
          const float sqb = fmaf(-2.0f, acc[mf][nf][r], c2v);   // biased, ordering-exact
          const unsigned x = (__float_as_uint(sqb) & 0xFFFFFF00u) | q;
          const unsigned a0 = kv[nf][0], a1 = kv[nf][1], a2 = kv[nf][2],
                         a3 = kv[nf][3], a4 = kv[nf][4];
          kv[nf][0] = a0 < x ? a0 : x;
          kv[nf][1] = med3u(a0, a1, x);
          kv[nf][2] = med3u(a1, a2, x);
          kv[nf][3] = med3u(a2, a3, x);
          kv[nf][4] = med3u(a3, a4, x);
        }
      }

    __builtin_amdgcn_sched_barrier(0);                   // reads stay above
    asm volatile("s_waitcnt lgkmcnt(0)" ::: "memory");   // our buf reads done
    __builtin_amdgcn_s_barrier();                        // all waves done reading
    __builtin_amdgcn_sched_barrier(0);                   // next stage stays below
  }

  // dump per-(slot,feature) lists: [128 feats][16 slots][5], stride 81 (pad)
  unsigned* mb = (unsigned*)&sC[0][0];
#pragma unroll
  for (int nf = 0; nf < 2; ++nf) {
    const int fl = wn * 32 + nf * 16 + lrow;
    const int s = wm * 4 + lk;
#pragma unroll
    for (int j = 0; j < 5; ++j) mb[fl * 81 + s * 5 + j] = kv[nf][j];
  }
  __syncthreads();

  if (tid < FB) {
    unsigned bv[8], bi[8];
#pragma unroll
    for (int j = 0; j < 8; ++j) { bv[j] = 0xFFFFFFFFu; bi[j] = 0; }
    const unsigned* row = mb + tid * 81;
    for (int s = 0; s < 16; ++s) {
      const unsigned aux = (unsigned)(cb * CBSZ + (s >> 2) * 32 + (s & 3) * 4);
#pragma unroll
      for (int j = 0; j < 5; ++j) {
        const unsigned v = row[s * 5 + j];
        const unsigned q = v & 255u;
        const unsigned ci = aux + (q >> 3) * 128 + ((q >> 2) & 1u) * 16 + (q & 3u);
        const bool s0 = v < bv[0], s1 = v < bv[1], s2 = v < bv[2], s3 = v < bv[3],
                   s4 = v < bv[4], s5 = v < bv[5], s6 = v < bv[6], s7 = v < bv[7];
        bv[7] = s6 ? bv[6] : (s7 ? v : bv[7]);  bi[7] = s6 ? bi[6] : (s7 ? ci : bi[7]);
        bv[6] = s5 ? bv[5] : (s6 ? v : bv[6]);  bi[6] = s5 ? bi[5] : (s6 ? ci : bi[6]);
        bv[5] = s4 ? bv[4] : (s5 ? v : bv[5]);  bi[5] = s4 ? bi[4] : (s5 ? ci : bi[5]);
        bv[4] = s3 ? bv[3] : (s4 ? v : bv[4]);  bi[4] = s3 ? bi[3] : (s4 ? ci : bi[4]);
        bv[3] = s2 ? bv[2] : (s3 ? v : bv[3]);  bi[3] = s2 ? bi[2] : (s3 ? ci : bi[3]);
        bv[2] = s1 ? bv[1] : (s2 ? v : bv[2]);  bi[2] = s1 ? bi[1] : (s2 ? ci : bi[2]);
        bv[1] = s0 ? bv[0] : (s1 ? v : bv[1]);  bi[1] = s0 ? bi[0] : (s1 ? ci : bi[1]);
        bv[0] = s0 ? v : bv[0];                 bi[0] = s0 ? ci : bi[0];
      }
    }
    uint2* cp = cand + ((size_t)(fbase + tid) * NCB + cb) * 8;
#pragma unroll
    for (int j = 0; j < 8; ++j) cp[j] = make_uint2(bv[j], bi[j]);
  }
}

// ---- select: bitonic top-12, exact rescore, top-5, softmax -> sel + counts -
__global__ __launch_bounds__(256) void k_select(
    const float* __restrict__ F, const float* __restrict__ A,
    const float* __restrict__ C, const float* __restrict__ c2g,
    const uint2* __restrict__ cand, uint4* __restrict__ sel,
    unsigned* __restrict__ cnt)
{
  const int l = threadIdx.x & 63, w = threadIdx.x >> 6;
  const int f = blockIdx.x * 4 + w;
  const int b = f >> 11;

  const float4 xv = *(const float4*)(F + (size_t)f * DDIM + l * 4);
  const float x2 = wsum(xv.x*xv.x + xv.y*xv.y + xv.z*xv.z + xv.w*xv.w);

  unsigned key = 0xFFFFFFFFu, ci = 0u;
  if (l < 32) { const uint2 e = cand[(size_t)f * 32 + l]; key = e.x; ci = e.y; }

#pragma unroll
  for (int k = 2; k <= 32; k <<= 1) {
#pragma unroll
    for (int j = k >> 1; j >= 1; j >>= 1) {
      const unsigned pk = __shfl_xor(key, j);
      const unsigned pc = __shfl_xor(ci, j);
      const bool keepMin = (((l & j) == 0) == ((l & k) == 0));
      const bool take = keepMin ? (pk < key) : (pk > key);
      if (take) { key = pk; ci = pc; }
    }
  }

  int sidx[RESC];
#pragma unroll
  for (int j = 0; j < RESC; ++j) sidx[j] = __shfl((int)ci, j);
  float4 cv[RESC];
#pragma unroll
  for (int j = 0; j < RESC; ++j)
    cv[j] = *(const float4*)(C + (size_t)sidx[j] * DDIM + l * 4);
  float sq[RESC];
#pragma unroll
  for (int j = 0; j < RESC; ++j) {
    const float d = wsum(xv.x*cv[j].x + xv.y*cv[j].y + xv.z*cv[j].z + xv.w*cv[j].w);
    sq[j] = fmaxf(fmaf(-2.0f, d, x2 + c2g[sidx[j]]), 0.0f);
  }

  unsigned sk[RESC];
#pragma unroll
  for (int j = 0; j < RESC; ++j) sk[j] = (__float_as_uint(sq[j]) & ~15u) | (unsigned)j;
  float ssq[TK]; int jm5[TK];
#pragma unroll
  for (int s = 0; s < TK; ++s) {
    unsigned m = 0xFFFFFFFFu;
#pragma unroll
    for (int j = 0; j < RESC; ++j) m = sk[j] < m ? sk[j] : m;
#pragma unroll
    for (int j = 0; j < RESC; ++j) sk[j] = (sk[j] == m) ? 0xFFFFFFFFu : sk[j];
    ssq[s] = __uint_as_float(m & ~15u);
    jm5[s] = (int)(m & 15u);
  }
  int k5[TK];
#pragma unroll
  for (int s = 0; s < TK; ++s) k5[s] = __shfl((int)ci, jm5[s]);

  const float d0 = sqrtf(ssq[0]);
  float p5[TK]; float sum = 0.f;
#pragma unroll
  for (int s = 0; s < TK; ++s) { p5[s] = expf(d0 - sqrtf(ssq[s])); sum += p5[s]; }
  const float inv = 1.0f / sum;
  const float att = A[f];

  float p = p5[0]; int ks = k5[0];
  p = (l == 1) ? p5[1] : p;  ks = (l == 1) ? k5[1] : ks;
  p = (l == 2) ? p5[2] : p;  ks = (l == 2) ? k5[2] : ks;
  p = (l == 3) ? p5[3] : p;  ks = (l == 3) ? k5[3] : ks;
  p = (l == 4) ? p5[4] : p;  ks = (l == 4) ? k5[4] : ks;
  p *= inv;
  if (l < TK) {
    sel[(size_t)f * TK + l] = make_uint4((unsigned)ks, __float_as_uint(p),
                                         __float_as_uint(att * p), 0u);
    atomicAdd(&cnt[b * KCENT + ks], 1u);
  }
}

// ---- single-block exclusive scan over cnt[65536] -> off --------------------
__global__ __launch_bounds__(1024) void k_scan(const unsigned* __restrict__ cnt,
                                               unsigned* __restrict__ off) {
  __shared__ unsigned wt[16];
  const int t = threadIdx.x, lane = t & 63, w = t >> 6;
  const uint4* src = (const uint4*)cnt + t * 16;
  uint4 v[16];
  unsigned tot = 0;
#pragma unroll
  for (int i = 0; i < 16; ++i) {
    v[i] = src[i];
    tot += v[i].x + v[i].y + v[i].z + v[i].w;
  }
  unsigned ws = tot;                       // inclusive wave scan of totals
#pragma unroll
  for (int d = 1; d < 64; d <<= 1) {
    const unsigned n = __shfl_up(ws, d);
    if (lane >= d) ws += n;
  }
  if (lane == 63) wt[w] = ws;
  __syncthreads();
  unsigned wbase = 0;
#pragma unroll
  for (int j = 0; j < 16; ++j) wbase += (j < w) ? wt[j] : 0u;
  unsigned ex = wbase + ws - tot;          // exclusive prefix for this thread
  uint4* dst = (uint4*)off + t * 16;
#pragma unroll
  for (int i = 0; i < 16; ++i) {
    uint4 o;
    o.x = ex; o.y = ex + v[i].x; o.z = o.y + v[i].y; o.w = o.z + v[i].z;
    ex = o.w + v[i].w;
    dst[i] = o;
  }
}

// ---- fill CSR entries ------------------------------------------------------
__global__ __launch_bounds__(256) void k_fill(const uint4* __restrict__ sel,
                                              unsigned* __restrict__ off,
                                              uint4* __restrict__ ent) {
  const int f = blockIdx.x * 256 + threadIdx.x;
  const int b = f >> 11;
#pragma unroll
  for (int s = 0; s < TK; ++s) {
    const uint4 e = sel[(size_t)f * TK + s];
    const unsigned pos = atomicAdd(&off[b * KCENT + (int)e.x], 1u);
    ent[pos] = make_uint4((unsigned)f, e.y, e.z, 0u);
  }
}

// ---- per-row gather + normalize + weight (atomic-free, single write) -------
__global__ __launch_bounds__(256) void k_out(
    const float* __restrict__ F, const float* __restrict__ C,
    const unsigned* __restrict__ cnt, const unsigned* __restrict__ offend,
    const uint4* __restrict__ ent, float* __restrict__ outG, float* __restrict__ outW)
{
  const int l = threadIdx.x & 63, w = threadIdx.x >> 6;
  const int row = blockIdx.x * 4 + w;
  const int k = row & (KCENT - 1);
  const unsigned c = cnt[row];
  const unsigned s0 = offend[row] - c;

  float4 acc = {0.f, 0.f, 0.f, 0.f};
  float csum = 0.f, pmax = 0.f;
  for (unsigned j = 0; j < c; ++j) {
    const uint4 E = ent[s0 + j];
    const float coef = __uint_as_float(E.z);
    const float pp = __uint_as_float(E.y);
    const float4 xr = *(const float4*)(F + (size_t)E.x * DDIM + l * 4);
    acc.x = fmaf(coef, xr.x, acc.x);
    acc.y = fmaf(coef, xr.y, acc.y);
    acc.z = fmaf(coef, xr.z, acc.z);
    acc.w = fmaf(coef, xr.w, acc.w);
    csum += coef; pmax = fmaxf(pmax, pp);
  }
  float4 o = {0.f, 0.f, 0.f, 0.f};
  if (c > 0) {
    const float4 cv = *(const float4*)(C + (size_t)k * DDIM + l * 4);
    o.x = fmaf(-csum, cv.x, acc.x);
    o.y = fmaf(-csum, cv.y, acc.y);
    o.z = fmaf(-csum, cv.z, acc.z);
    o.w = fmaf(-csum, cv.w, acc.w);
    const float ss = wsum(o.x*o.x + o.y*o.y + o.z*o.z + o.w*o.w);
    const float sc = 1.0f / (sqrtf(ss) + 1e-6f);
    o.x *= sc; o.y *= sc; o.z *= sc; o.w *= sc;
  }
  *(float4*)(outG + (size_t)row * DDIM + l * 4) = o;
  if (l == 0) outW[row] = pmax;
}

extern "C" void kernel_launch(void* const* d_in, const int* in_sizes, int n_in,
                              void* d_out, int out_size, void* d_ws, size_t ws_size,
                              hipStream_t stream) {
  const float* F = (const float*)d_in[0];
  const float* A = (const float*)d_in[1];
  const float* C = (const float*)d_in[2];
  float* outG = (float*)d_out;
  float* outW = outG + (size_t)BDIM * KCENT * DDIM;

  char* ws = (char*)d_ws;
  short*    Xbf  = (short*)ws;                       // [0,4M)  dead after k_main
  short*    Cbf  = (short*)(ws + (4u << 20));        // [4M,12M)
  float*    c2   = (float*)(ws + (12u << 20));       // [12M, +64K)
  unsigned* cnt  = (unsigned*)(ws + (12u << 20) + (64u << 10));   // +256K  (NO overlay!)
  uint2*    cand = (uint2*)(ws + (13u << 20));       // [13M,15M)
  // overlay region [0,4M) reused strictly AFTER k_main:
  uint4*    sel  = (uint4*)ws;                       // 640 KB
  unsigned* off  = (unsigned*)(ws + (1536u << 10));  // 256 KB
  uint4*    ent  = (uint4*)(ws + (2u << 20));        // 640 KB

  k_cvtall<<<1024 + KCENT / 4 + 64, 256, 0, stream>>>(F, C, Xbf, Cbf, c2, cnt);
  k_main  <<<(BDIM * NFEAT / FB) * NCB, 1024, 0, stream>>>(Xbf, Cbf, c2, cand);
  k_select<<<BDIM * NFEAT / 4, 256, 0, stream>>>(F, A, C, c2, cand, sel, cnt);
  k_scan  <<<1, 1024, 0, stream>>>(cnt, off);
  k_fill  <<<BDIM * NFEAT / 256, 256, 0, stream>>>(sel, off, ent);
  k_out   <<<NROW / 4, 256, 0, stream>>>(F, C, cnt, off, ent, outG, outW);
}

// Round 13
// 186.895 us; speedup vs baseline: 1.0673x; 1.0673x over previous
//
#include <hip/hip_runtime.h>
#include <hip/hip_bf16.h>
#include <math.h>

#define BDIM  4
#define NFEAT 2048
#define DDIM  256
#define KCENT 16384
#define TK    5
#define NCB   4
#define CBSZ  (KCENT / NCB)   // 4096
#define KB    128             // centroids per tile
#define NT    (CBSZ / KB)     // 32
#define FB    128             // features per block
#define RESC  12              // exactly-rescored candidates per feature
#define NROW  (BDIM * KCENT)  // 65536
#define INFF  (__builtin_inff())

typedef __attribute__((ext_vector_type(4))) float  f32x4;
typedef __attribute__((ext_vector_type(8))) short  short8v;

static __device__ __forceinline__ short f2bf(float x) {
  __hip_bfloat16 h = __float2bfloat16(x);
  return __builtin_bit_cast(short, h);
}

static __device__ __forceinline__ float wsum(float v) {
  v += __shfl_xor(v, 1);  v += __shfl_xor(v, 2);  v += __shfl_xor(v, 4);
  v += __shfl_xor(v, 8);  v += __shfl_xor(v, 16); v += __shfl_xor(v, 32);
  return v;
}
static __device__ __forceinline__ unsigned uwsum(unsigned v) {
  v += __shfl_xor(v, 1);  v += __shfl_xor(v, 2);  v += __shfl_xor(v, 4);
  v += __shfl_xor(v, 8);  v += __shfl_xor(v, 16); v += __shfl_xor(v, 32);
  return v;
}
static __device__ __forceinline__ unsigned med3u(unsigned a, unsigned b, unsigned c) {
  unsigned d;
  asm("v_med3_u32 %0, %1, %2, %3" : "=v"(d) : "v"(a), "v"(b), "v"(c));
  return d;
}

// ---- fused prep: F->bf16 | C->bf16 + c2 | zero cnt (cnt OUTSIDE overlays) --
__global__ __launch_bounds__(256) void k_cvtall(const float* __restrict__ F,
                                                const float* __restrict__ C,
                                                short* __restrict__ Xbf,
                                                short* __restrict__ Cbf,
                                                float* __restrict__ c2,
                                                unsigned* __restrict__ cnt) {
  if (blockIdx.x < 1024) {
    const int i = blockIdx.x * 256 + threadIdx.x;      // 262144 x 8 elems
    const float4* s = (const float4*)F + (size_t)i * 2;
    const float4 a = s[0], b = s[1];
    short8v o;
    o[0] = f2bf(a.x); o[1] = f2bf(a.y); o[2] = f2bf(a.z); o[3] = f2bf(a.w);
    o[4] = f2bf(b.x); o[5] = f2bf(b.y); o[6] = f2bf(b.z); o[7] = f2bf(b.w);
    ((short8v*)Xbf)[i] = o;
  } else if (blockIdx.x < 1024 + KCENT / 4) {
    const int w = threadIdx.x >> 6, l = threadIdx.x & 63;
    const int row = (blockIdx.x - 1024) * 4 + w;
    const float4 v = *(const float4*)(C + (size_t)row * DDIM + l * 4);
    short4 o;
    o.x = f2bf(v.x); o.y = f2bf(v.y); o.z = f2bf(v.z); o.w = f2bf(v.w);
    *(short4*)(Cbf + (size_t)row * DDIM + l * 4) = o;
    const float ss = wsum(v.x*v.x + v.y*v.y + v.z*v.z + v.w*v.w);
    if (l == 0) c2[row] = ss;
  } else {
    const int i = (blockIdx.x - (1024 + KCENT / 4)) * 256 + threadIdx.x;
    ((uint4*)cnt)[i] = make_uint4(0u, 0u, 0u, 0u);     // 64 blocks x 4 KB
  }
}

// ---- bf16 MFMA distance pass, med3 min-list, top-8/feature -----------------
__global__ __launch_bounds__(1024, 4) void k_main(
    const short* __restrict__ Xbf, const short* __restrict__ Cbf,
    const float* __restrict__ c2g, uint2* __restrict__ cand)
{
  __shared__ short sC[2][KB * DDIM];   // 2 x 64 KB
  __shared__ float sC2a[CBSZ];         // 16 KB: whole split's biased c2

  const int tid = threadIdx.x;
  const int l = tid & 63, w = tid >> 6;        // w in [0,16)
  const int wm = w & 3, wn = w >> 2;           // 4 cent-groups x 4 feat-groups
  const int lrow = l & 15, lk = l >> 4;
  const int cb = (blockIdx.x & 7) >> 1;
  const int fb = (blockIdx.x >> 3) * 2 + (blockIdx.x & 1);
  const int fbase = fb * FB;
  const size_t coffB = (size_t)cb * CBSZ * (DDIM * 2);

  const int poff = (tid >> 9) * 8192 + (tid & 15) * 512 +
                   ((tid >> 6) & 7) * 64 + ((tid >> 4) & 3) * 16;

  auto stage = [&](const char* gsrcB, int buf) {   // 64 KB in 4 x (1024x16B)
#pragma unroll
    for (int r = 0; r < 4; ++r) {
      __builtin_amdgcn_global_load_lds(
          (const __attribute__((address_space(1))) void*)(gsrcB + r * 16384 + poff),
          (__attribute__((address_space(3))) void*)((char*)&sC[buf][0] + r * 16384 + tid * 16),
          16, 0, 0);
    }
  };

  stage((const char*)Xbf + (size_t)fbase * 512, 1);
  stage((const char*)Cbf + coffB, 0);
  {
    const f32x4* src = (const f32x4*)(c2g + cb * CBSZ);
    const f32x4 bias = {1024.f, 1024.f, 1024.f, 1024.f};
    ((f32x4*)sC2a)[tid] = src[tid] + bias;     // 1024 x 16B = 16 KB exactly
  }
  __syncthreads();

  // feature fragments -> registers (feature = wn*32 + nf*16 + lrow)
  short8v bfr[2][8];                            // 64 VGPR
#pragma unroll
  for (int nf = 0; nf < 2; ++nf) {
    const char* bp = (const char*)&sC[1][0] + (wn * 2 + nf) * 8192 + l * 16;
#pragma unroll
    for (int kk = 0; kk < 8; ++kk)
      bfr[nf][kk] = *(const short8v*)(bp + kk * 1024);
  }
  __syncthreads();   // buf1 free for staging

  const char* a0b0 = (const char*)&sC[0][0] + (wm * 2 + 0) * 8192 + l * 16;
  const char* a1b0 = (const char*)&sC[0][0] + (wm * 2 + 1) * 8192 + l * 16;
  const char* a0b1 = (const char*)&sC[1][0] + (wm * 2 + 0) * 8192 + l * 16;
  const char* a1b1 = (const char*)&sC[1][0] + (wm * 2 + 1) * 8192 + l * 16;

  unsigned kv[2][5];
#pragma unroll
  for (int nf = 0; nf < 2; ++nf)
#pragma unroll
    for (int j = 0; j < 5; ++j) kv[nf][j] = 0xFFFFFFFFu;

  for (int t = 0; t < NT; ++t) {
    const int buf = t & 1;
    if (t + 1 < NT) {
      stage((const char*)Cbf + coffB + (size_t)(t + 1) * (KB * 512), buf ^ 1);
      __builtin_amdgcn_sched_barrier(0);                 // stage pinned above
      asm volatile("s_waitcnt vmcnt(4)" ::: "memory");   // tile t's 4 retired
    } else {
      __builtin_amdgcn_sched_barrier(0);
      asm volatile("s_waitcnt vmcnt(0)" ::: "memory");
    }
    __builtin_amdgcn_s_barrier();                        // tile t landed (all)
    __builtin_amdgcn_sched_barrier(0);                   // no reads hoist above

    f32x4 acc[2][2];
    const f32x4 z = {0.f, 0.f, 0.f, 0.f};
#pragma unroll
    for (int mf = 0; mf < 2; ++mf)
#pragma unroll
      for (int nf = 0; nf < 2; ++nf) acc[mf][nf] = z;

    const char* ap0 = buf ? a0b1 : a0b0;
    const char* ap1 = buf ? a1b1 : a1b0;
#pragma unroll
    for (int kk = 0; kk < 8; ++kk) {
      const short8v a0 = *(const short8v*)(ap0 + kk * 1024);
      const short8v a1 = *(const short8v*)(ap1 + kk * 1024);
#pragma unroll
      for (int nf = 0; nf < 2; ++nf) {
        acc[0][nf] = __builtin_amdgcn_mfma_f32_16x16x32_bf16(a0, bfr[nf][kk], acc[0][nf], 0, 0, 0);
        acc[1][nf] = __builtin_amdgcn_mfma_f32_16x16x32_bf16(a1, bfr[nf][kk], acc[1][nf], 0, 0, 0);
      }
    }

    const f32x4 cb0 = *(const f32x4*)&sC2a[t * KB + wm * 32 + lk * 4];
    const f32x4 cb1 = *(const f32x4*)&sC2a[t * KB + wm * 32 + 16 + lk * 4];
#pragma unroll
    for (int mf = 0; mf < 2; ++mf)
#pragma unroll
      for (int r = 0; r < 4; ++r) {
        const float c2v = mf ? cb1[r] : cb0[r];
        const unsigned q = (unsigned)(t * 8 + mf * 4 + r);
#pragma unroll
        for (int nf = 0; nf < 2; ++nf) {
          const float sqb = fmaf(-2.0f, acc[mf][nf][r], c2v);   // biased, ordering-exact
          const unsigned x = (__float_as_uint(sqb) & 0xFFFFFF00u) | q;
          const unsigned a0 = kv[nf][0], a1 = kv[nf][1], a2 = kv[nf][2],
                         a3 = kv[nf][3], a4 = kv[nf][4];
          kv[nf][0] = a0 < x ? a0 : x;
          kv[nf][1] = med3u(a0, a1, x);
          kv[nf][2] = med3u(a1, a2, x);
          kv[nf][3] = med3u(a2, a3, x);
          kv[nf][4] = med3u(a3, a4, x);
        }
      }

    __builtin_amdgcn_sched_barrier(0);                   // reads stay above
    asm volatile("s_waitcnt lgkmcnt(0)" ::: "memory");   // our buf reads done
    __builtin_amdgcn_s_barrier();                        // all waves done reading
    __builtin_amdgcn_sched_barrier(0);                   // next stage stays below
  }

  // dump per-(slot,feature) lists: [128 feats][16 slots][5], stride 81 (pad)
  unsigned* mb = (unsigned*)&sC[0][0];
#pragma unroll
  for (int nf = 0; nf < 2; ++nf) {
    const int fl = wn * 32 + nf * 16 + lrow;
    const int s = wm * 4 + lk;
#pragma unroll
    for (int j = 0; j < 5; ++j) mb[fl * 81 + s * 5 + j] = kv[nf][j];
  }
  __syncthreads();

  if (tid < FB) {
    unsigned bv[8], bi[8];
#pragma unroll
    for (int j = 0; j < 8; ++j) { bv[j] = 0xFFFFFFFFu; bi[j] = 0; }
    const unsigned* row = mb + tid * 81;
    for (int s = 0; s < 16; ++s) {
      const unsigned aux = (unsigned)(cb * CBSZ + (s >> 2) * 32 + (s & 3) * 4);
#pragma unroll
      for (int j = 0; j < 5; ++j) {
        const unsigned v = row[s * 5 + j];
        const unsigned q = v & 255u;
        const unsigned ci = aux + (q >> 3) * 128 + ((q >> 2) & 1u) * 16 + (q & 3u);
        const bool s0 = v < bv[0], s1 = v < bv[1], s2 = v < bv[2], s3 = v < bv[3],
                   s4 = v < bv[4], s5 = v < bv[5], s6 = v < bv[6], s7 = v < bv[7];
        bv[7] = s6 ? bv[6] : (s7 ? v : bv[7]);  bi[7] = s6 ? bi[6] : (s7 ? ci : bi[7]);
        bv[6] = s5 ? bv[5] : (s6 ? v : bv[6]);  bi[6] = s5 ? bi[5] : (s6 ? ci : bi[6]);
        bv[5] = s4 ? bv[4] : (s5 ? v : bv[5]);  bi[5] = s4 ? bi[4] : (s5 ? ci : bi[5]);
        bv[4] = s3 ? bv[3] : (s4 ? v : bv[4]);  bi[4] = s3 ? bi[3] : (s4 ? ci : bi[4]);
        bv[3] = s2 ? bv[2] : (s3 ? v : bv[3]);  bi[3] = s2 ? bi[2] : (s3 ? ci : bi[3]);
        bv[2] = s1 ? bv[1] : (s2 ? v : bv[2]);  bi[2] = s1 ? bi[1] : (s2 ? ci : bi[2]);
        bv[1] = s0 ? bv[0] : (s1 ? v : bv[1]);  bi[1] = s0 ? bi[0] : (s1 ? ci : bi[1]);
        bv[0] = s0 ? v : bv[0];                 bi[0] = s0 ? ci : bi[0];
      }
    }
    uint2* cp = cand + ((size_t)(fbase + tid) * NCB + cb) * 8;
#pragma unroll
    for (int j = 0; j < 8; ++j) cp[j] = make_uint2(bv[j], bi[j]);
  }
}

// ---- select: bitonic top-12, exact rescore, top-5, softmax -> sel + counts -
__global__ __launch_bounds__(256) void k_select(
    const float* __restrict__ F, const float* __restrict__ A,
    const float* __restrict__ C, const float* __restrict__ c2g,
    const uint2* __restrict__ cand, uint4* __restrict__ sel,
    unsigned* __restrict__ cnt)
{
  const int l = threadIdx.x & 63, w = threadIdx.x >> 6;
  const int f = blockIdx.x * 4 + w;
  const int b = f >> 11;

  const float4 xv = *(const float4*)(F + (size_t)f * DDIM + l * 4);
  const float x2 = wsum(xv.x*xv.x + xv.y*xv.y + xv.z*xv.z + xv.w*xv.w);

  unsigned key = 0xFFFFFFFFu, ci = 0u;
  if (l < 32) { const uint2 e = cand[(size_t)f * 32 + l]; key = e.x; ci = e.y; }

#pragma unroll
  for (int k = 2; k <= 32; k <<= 1) {
#pragma unroll
    for (int j = k >> 1; j >= 1; j >>= 1) {
      const unsigned pk = __shfl_xor(key, j);
      const unsigned pc = __shfl_xor(ci, j);
      const bool keepMin = (((l & j) == 0) == ((l & k) == 0));
      const bool take = keepMin ? (pk < key) : (pk > key);
      if (take) { key = pk; ci = pc; }
    }
  }

  int sidx[RESC];
#pragma unroll
  for (int j = 0; j < RESC; ++j) sidx[j] = __shfl((int)ci, j);
  float4 cv[RESC];
#pragma unroll
  for (int j = 0; j < RESC; ++j)
    cv[j] = *(const float4*)(C + (size_t)sidx[j] * DDIM + l * 4);
  float sq[RESC];
#pragma unroll
  for (int j = 0; j < RESC; ++j) {
    const float d = wsum(xv.x*cv[j].x + xv.y*cv[j].y + xv.z*cv[j].z + xv.w*cv[j].w);
    sq[j] = fmaxf(fmaf(-2.0f, d, x2 + c2g[sidx[j]]), 0.0f);
  }

  unsigned sk[RESC];
#pragma unroll
  for (int j = 0; j < RESC; ++j) sk[j] = (__float_as_uint(sq[j]) & ~15u) | (unsigned)j;
  float ssq[TK]; int jm5[TK];
#pragma unroll
  for (int s = 0; s < TK; ++s) {
    unsigned m = 0xFFFFFFFFu;
#pragma unroll
    for (int j = 0; j < RESC; ++j) m = sk[j] < m ? sk[j] : m;
#pragma unroll
    for (int j = 0; j < RESC; ++j) sk[j] = (sk[j] == m) ? 0xFFFFFFFFu : sk[j];
    ssq[s] = __uint_as_float(m & ~15u);
    jm5[s] = (int)(m & 15u);
  }
  int k5[TK];
#pragma unroll
  for (int s = 0; s < TK; ++s) k5[s] = __shfl((int)ci, jm5[s]);

  const float d0 = sqrtf(ssq[0]);
  float p5[TK]; float sum = 0.f;
#pragma unroll
  for (int s = 0; s < TK; ++s) { p5[s] = expf(d0 - sqrtf(ssq[s])); sum += p5[s]; }
  const float inv = 1.0f / sum;
  const float att = A[f];

  float p = p5[0]; int ks = k5[0];
  p = (l == 1) ? p5[1] : p;  ks = (l == 1) ? k5[1] : ks;
  p = (l == 2) ? p5[2] : p;  ks = (l == 2) ? k5[2] : ks;
  p = (l == 3) ? p5[3] : p;  ks = (l == 3) ? k5[3] : ks;
  p = (l == 4) ? p5[4] : p;  ks = (l == 4) ? k5[4] : ks;
  p *= inv;
  if (l < TK) {
    sel[(size_t)f * TK + l] = make_uint4((unsigned)ks, __float_as_uint(p),
                                         __float_as_uint(att * p), 0u);
    atomicAdd(&cnt[b * KCENT + ks], 1u);
  }
}

// ---- prefix scan over cnt[65536]: parallel 3-kernel trio (round-10 proven) -
__global__ __launch_bounds__(256) void k_scan1(const unsigned* __restrict__ cnt,
                                               unsigned* __restrict__ bsum) {
  __shared__ unsigned ws4[4];
  const int t = threadIdx.x, lane = t & 63, w = t >> 6;
  const uint4 c = *(const uint4*)&cnt[(blockIdx.x * 256 + t) * 4];
  unsigned v = uwsum(c.x + c.y + c.z + c.w);
  if (lane == 0) ws4[w] = v;
  __syncthreads();
  if (t == 0) bsum[blockIdx.x] = ws4[0] + ws4[1] + ws4[2] + ws4[3];
}

__global__ __launch_bounds__(64) void k_scan2(const unsigned* __restrict__ bsum,
                                              unsigned* __restrict__ boff) {
  const int l = threadIdx.x;
  unsigned v = bsum[l];
  const unsigned own = v;
#pragma unroll
  for (int d = 1; d < 64; d <<= 1) {
    const unsigned n = __shfl_up(v, d);
    if (l >= d) v += n;
  }
  boff[l] = v - own;
}

__global__ __launch_bounds__(256) void k_scan3(const unsigned* __restrict__ cnt,
                                               const unsigned* __restrict__ boff,
                                               unsigned* __restrict__ off) {
  __shared__ unsigned wt[4];
  const int t = threadIdx.x, lane = t & 63, w = t >> 6;
  const int i0 = (blockIdx.x * 256 + t) * 4;
  const uint4 c = *(const uint4*)&cnt[i0];
  const unsigned ts = c.x + c.y + c.z + c.w;
  unsigned v = ts;
#pragma unroll
  for (int d = 1; d < 64; d <<= 1) {
    const unsigned n = __shfl_up(v, d);
    if (lane >= d) v += n;
  }
  if (lane == 63) wt[w] = v;
  __syncthreads();
  unsigned wb = boff[blockIdx.x];
  if (w > 0) wb += wt[0];
  if (w > 1) wb += wt[1];
  if (w > 2) wb += wt[2];
  const unsigned ex = wb + v - ts;
  uint4 o;
  o.x = ex; o.y = ex + c.x; o.z = o.y + c.y; o.w = o.z + c.z;
  *(uint4*)&off[i0] = o;
}

// ---- fill CSR entries ------------------------------------------------------
__global__ __launch_bounds__(256) void k_fill(const uint4* __restrict__ sel,
                                              unsigned* __restrict__ off,
                                              uint4* __restrict__ ent) {
  const int f = blockIdx.x * 256 + threadIdx.x;
  const int b = f >> 11;
#pragma unroll
  for (int s = 0; s < TK; ++s) {
    const uint4 e = sel[(size_t)f * TK + s];
    const unsigned pos = atomicAdd(&off[b * KCENT + (int)e.x], 1u);
    ent[pos] = make_uint4((unsigned)f, e.y, e.z, 0u);
  }
}

// ---- per-row gather + normalize + weight (atomic-free, single write) -------
__global__ __launch_bounds__(256) void k_out(
    const float* __restrict__ F, const float* __restrict__ C,
    const unsigned* __restrict__ cnt, const unsigned* __restrict__ offend,
    const uint4* __restrict__ ent, float* __restrict__ outG, float* __restrict__ outW)
{
  const int l = threadIdx.x & 63, w = threadIdx.x >> 6;
  const int row = blockIdx.x * 4 + w;
  const int k = row & (KCENT - 1);
  const unsigned c = cnt[row];
  const unsigned s0 = offend[row] - c;

  float4 acc = {0.f, 0.f, 0.f, 0.f};
  float csum = 0.f, pmax = 0.f;
  for (unsigned j = 0; j < c; ++j) {
    const uint4 E = ent[s0 + j];
    const float coef = __uint_as_float(E.z);
    const float pp = __uint_as_float(E.y);
    const float4 xr = *(const float4*)(F + (size_t)E.x * DDIM + l * 4);
    acc.x = fmaf(coef, xr.x, acc.x);
    acc.y = fmaf(coef, xr.y, acc.y);
    acc.z = fmaf(coef, xr.z, acc.z);
    acc.w = fmaf(coef, xr.w, acc.w);
    csum += coef; pmax = fmaxf(pmax, pp);
  }
  float4 o = {0.f, 0.f, 0.f, 0.f};
  if (c > 0) {
    const float4 cv = *(const float4*)(C + (size_t)k * DDIM + l * 4);
    o.x = fmaf(-csum, cv.x, acc.x);
    o.y = fmaf(-csum, cv.y, acc.y);
    o.z = fmaf(-csum, cv.z, acc.z);
    o.w = fmaf(-csum, cv.w, acc.w);
    const float ss = wsum(o.x*o.x + o.y*o.y + o.z*o.z + o.w*o.w);
    const float sc = 1.0f / (sqrtf(ss) + 1e-6f);
    o.x *= sc; o.y *= sc; o.z *= sc; o.w *= sc;
  }
  *(float4*)(outG + (size_t)row * DDIM + l * 4) = o;
  if (l == 0) outW[row] = pmax;
}

extern "C" void kernel_launch(void* const* d_in, const int* in_sizes, int n_in,
                              void* d_out, int out_size, void* d_ws, size_t ws_size,
                              hipStream_t stream) {
  const float* F = (const float*)d_in[0];
  const float* A = (const float*)d_in[1];
  const float* C = (const float*)d_in[2];
  float* outG = (float*)d_out;
  float* outW = outG + (size_t)BDIM * KCENT * DDIM;

  char* ws = (char*)d_ws;
  short*    Xbf  = (short*)ws;                       // [0,4M)  dead after k_main
  short*    Cbf  = (short*)(ws + (4u << 20));        // [4M,12M)
  float*    c2   = (float*)(ws + (12u << 20));       // [12M, +64K)
  unsigned* cnt  = (unsigned*)(ws + (12u << 20) + (64u << 10));    // 256 KB, no overlay
  unsigned* bsum = (unsigned*)(ws + (12u << 20) + (320u << 10));   // 256 B, no overlay
  unsigned* boff = (unsigned*)(ws + (12u << 20) + (324u << 10));   // 256 B, no overlay
  uint2*    cand = (uint2*)(ws + (13u << 20));       // [13M,15M)
  // overlay region [0,4M) reused strictly AFTER k_main:
  uint4*    sel  = (uint4*)ws;                       // 640 KB
  unsigned* off  = (unsigned*)(ws + (1536u << 10));  // 256 KB
  uint4*    ent  = (uint4*)(ws + (2u << 20));        // 640 KB

  k_cvtall<<<1024 + KCENT / 4 + 64, 256, 0, stream>>>(F, C, Xbf, Cbf, c2, cnt);
  k_main  <<<(BDIM * NFEAT / FB) * NCB, 1024, 0, stream>>>(Xbf, Cbf, c2, cand);
  k_select<<<BDIM * NFEAT / 4, 256, 0, stream>>>(F, A, C, c2, cand, sel, cnt);
  k_scan1 <<<NROW / 1024, 256, 0, stream>>>(cnt, bsum);
  k_scan2 <<<1, 64, 0, stream>>>(bsum, boff);
  k_scan3 <<<NROW / 1024, 256, 0, stream>>>(cnt, boff, off);
  k_fill  <<<BDIM * NFEAT / 256, 256, 0, stream>>>(sel, off, ent);
  k_out   <<<NROW / 4, 256, 0, stream>>>(F, C, cnt, off, ent, outG, outW);
}